// Round 4
// baseline (410.045 us; speedup 1.0000x reference)
//
#include <hip/hip_runtime.h>
#include <math.h>

#define BATCH 128

// ============================================================================
// Layer 1 (fused transpose + conv + select + pool):
// x [128][3][2048] -> X2 [1024][8][128]  (batch-minor)
// Block: 256 thr, tiles 64 n x 64 b through LDS.
// ============================================================================
__global__ __launch_bounds__(256) void l1_kernel(
    const float* __restrict__ x, const float* __restrict__ W,
    const float* __restrict__ bias, const int* __restrict__ sel,
    float* __restrict__ Xout)
{
    __shared__ float tile[3][64][65];   // [c][n_local][b_local]
    __shared__ float wl[72];
    __shared__ float bl[24];
    int tid = threadIdx.x;
    int n0 = blockIdx.x * 64;
    int b0 = blockIdx.y * 64;
    if (tid < 72) wl[tid] = W[tid];
    if (tid >= 128 && tid < 152) bl[tid - 128] = bias[tid - 128];

    int ln = tid & 63;
    int bg = tid >> 6;
#pragma unroll
    for (int c = 0; c < 3; ++c)
#pragma unroll
        for (int j = 0; j < 16; ++j) {
            int bloc = bg * 16 + j;
            // coalesced along n (ln)
            tile[c][ln][bloc] = x[(size_t)(b0 + bloc) * 6144 + c * 2048 + n0 + ln];
        }
    __syncthreads();

    // wave bg handles 8 n-pairs; lane = b
    for (int pp = 0; pp < 8; ++pp) {
        int p  = bg * 8 + pp;        // local pair 0..31
        int ng = n0 + 2 * p;
        int s0 = sel[ng];
        int s1 = sel[ng + 1];
        float xa0 = tile[0][2*p][ln],   xa1 = tile[1][2*p][ln],   xa2 = tile[2][2*p][ln];
        float xb0 = tile[0][2*p+1][ln], xb1 = tile[1][2*p+1][ln], xb2 = tile[2][2*p+1][ln];
        int npair = (n0 >> 1) + p;
#pragma unroll
        for (int f = 0; f < 8; ++f) {
            int r0 = f * 3 + s0, r1 = f * 3 + s1;
            float z0 = fmaf(wl[r0*3+2], xa2, fmaf(wl[r0*3+1], xa1, fmaf(wl[r0*3+0], xa0, bl[r0])));
            float z1 = fmaf(wl[r1*3+2], xb2, fmaf(wl[r1*3+1], xb1, fmaf(wl[r1*3+0], xb0, bl[r1])));
            Xout[((size_t)npair * 8 + f) * 128 + b0 + ln] = fmaxf(fmaxf(z0, z1), 0.f);
        }
    }
}

// ============================================================================
// Batch-minor kd-conv layer:
//  X [2*NP][CIN][128] -> Xout [NP][CF][128]
//  lane <-> batch, TF f-values per thread, W read as wave-uniform float4
//  broadcasts along k (original [3*CF][CIN] layout, no packing).
//  KS waves split K; combine through LDS.
// ============================================================================
template<int CIN, int CF, int NP, int TF, int KS>
__global__ __launch_bounds__(64 * KS) void bm_kernel(
    const float* __restrict__ X,
    const float* __restrict__ W,
    const float* __restrict__ bias,
    const int*   __restrict__ sel,
    float* __restrict__ Xout)
{
    const int lane = threadIdx.x & 63;
    const int kw   = threadIdx.x >> 6;
    const int n    = blockIdx.x;
    const int f0   = blockIdx.y * TF;
    const int b0   = blockIdx.z << 6;

    const int s0 = sel[2 * n];
    const int s1 = sel[2 * n + 1];

    constexpr int KC = CIN / KS;
    const int k0 = kw * KC;

    const float* xp0 = X + ((size_t)(2 * n) * CIN + k0) * 128 + b0 + lane;
    const float* xp1 = xp0 + (size_t)CIN * 128;

    float acc0[TF], acc1[TF];
#pragma unroll
    for (int t = 0; t < TF; ++t) { acc0[t] = 0.f; acc1[t] = 0.f; }

#pragma unroll 2
    for (int kq = 0; kq < KC; kq += 4) {
        float4 wa[TF], wb[TF];
#pragma unroll
        for (int t = 0; t < TF; ++t) {
            wa[t] = *(const float4*)(W + (size_t)((f0 + t) * 3 + s0) * CIN + k0 + kq);
            wb[t] = *(const float4*)(W + (size_t)((f0 + t) * 3 + s1) * CIN + k0 + kq);
        }
        float xa0 = xp0[(kq + 0) * 128];
        float xa1 = xp0[(kq + 1) * 128];
        float xa2 = xp0[(kq + 2) * 128];
        float xa3 = xp0[(kq + 3) * 128];
        float xb0 = xp1[(kq + 0) * 128];
        float xb1 = xp1[(kq + 1) * 128];
        float xb2 = xp1[(kq + 2) * 128];
        float xb3 = xp1[(kq + 3) * 128];
#pragma unroll
        for (int t = 0; t < TF; ++t) {
            acc0[t] = fmaf(wa[t].x, xa0, acc0[t]);
            acc0[t] = fmaf(wa[t].y, xa1, acc0[t]);
            acc0[t] = fmaf(wa[t].z, xa2, acc0[t]);
            acc0[t] = fmaf(wa[t].w, xa3, acc0[t]);
            acc1[t] = fmaf(wb[t].x, xb0, acc1[t]);
            acc1[t] = fmaf(wb[t].y, xb1, acc1[t]);
            acc1[t] = fmaf(wb[t].z, xb2, acc1[t]);
            acc1[t] = fmaf(wb[t].w, xb3, acc1[t]);
        }
    }

    if constexpr (KS > 1) {
        __shared__ float sh[KS - 1][2 * TF][64];
        if (kw > 0) {
#pragma unroll
            for (int t = 0; t < TF; ++t) {
                sh[kw - 1][t][lane]      = acc0[t];
                sh[kw - 1][TF + t][lane] = acc1[t];
            }
        }
        __syncthreads();
        if (kw == 0) {
#pragma unroll
            for (int w = 0; w < KS - 1; ++w)
#pragma unroll
                for (int t = 0; t < TF; ++t) {
                    acc0[t] += sh[w][t][lane];
                    acc1[t] += sh[w][TF + t][lane];
                }
        }
    }

    if (kw == 0) {
#pragma unroll
        for (int t = 0; t < TF; ++t) {
            float bi0 = bias[(f0 + t) * 3 + s0];
            float bi1 = bias[(f0 + t) * 3 + s1];
            float v = fmaxf(fmaxf(acc0[t] + bi0, acc1[t] + bi1), 0.f);
            Xout[((size_t)n * CF + f0 + t) * 128 + b0 + lane] = v;
        }
    }
}

// ============================================================================
// FC head: h stored batch-minor [1024][128]; out[b][k] log-softmax, [128][16]
// one block (256 threads) per batch row
// ============================================================================
__global__ __launch_bounds__(256) void fc_logsoftmax_kernel(
    const float* __restrict__ h, const float* __restrict__ fcW,
    const float* __restrict__ fcb, float* __restrict__ out)
{
    int b   = blockIdx.x;
    int tid = threadIdx.x;
    int k     = tid & 15;
    int chunk = tid >> 4;

    const float* __restrict__ wk = fcW + (size_t)k * 1024;

    float partial = 0.0f;
    int j0 = chunk * 64;
#pragma unroll 8
    for (int j = 0; j < 64; ++j)
        partial = fmaf(h[(size_t)(j0 + j) * 128 + b], wk[j0 + j], partial);

    __shared__ float red[16][17];
    red[chunk][k] = partial;
    __syncthreads();

    __shared__ float logits[16];
    if (tid < 16) {
        float s = fcb[tid];
#pragma unroll
        for (int c = 0; c < 16; ++c) s += red[c][tid];
        logits[tid] = s;
    }
    __syncthreads();

    if (tid < 16) {
        float mx = -INFINITY;
#pragma unroll
        for (int kk = 0; kk < 16; ++kk) mx = fmaxf(mx, logits[kk]);
        float se = 0.0f;
#pragma unroll
        for (int kk = 0; kk < 16; ++kk) se += expf(logits[kk] - mx);
        out[b * 16 + tid] = logits[tid] - mx - logf(se);
    }
}

// ============================================================================
extern "C" void kernel_launch(void* const* d_in, const int* in_sizes, int n_in,
                              void* d_out, int out_size, void* d_ws, size_t ws_size,
                              hipStream_t stream)
{
    const float* x   = (const float*)d_in[0];
    const float* fcW = (const float*)d_in[34];
    const float* fcb = (const float*)d_in[35];

    float* buf0 = (float*)d_ws;
    float* buf1 = (float*)d_ws + (2u * 1024u * 1024u);   // 8 MB slots

#define WL(i) (const float*)d_in[1 + 3 * (i)]
#define BL(i) (const float*)d_in[2 + 3 * (i)]
#define SL(i) (const int*)  d_in[3 + 3 * (i)]

    // L1: x -> buf0  X2 [1024][8][128]
    l1_kernel<<<dim3(32, 2), 256, 0, stream>>>(x, WL(0), BL(0), SL(0), buf0);

    // L2: [1024][8][128] -> [512][32][128]
    bm_kernel<8, 32, 512, 8, 1><<<dim3(512, 4, 2), 64, 0, stream>>>(buf0, WL(1), BL(1), SL(1), buf1);
    // L3: -> [256][64][128]
    bm_kernel<32, 64, 256, 8, 1><<<dim3(256, 8, 2), 64, 0, stream>>>(buf1, WL(2), BL(2), SL(2), buf0);
    // L4: -> [128][64][128]
    bm_kernel<64, 64, 128, 8, 1><<<dim3(128, 8, 2), 64, 0, stream>>>(buf0, WL(3), BL(3), SL(3), buf1);
    // L5: -> [64][64][128]
    bm_kernel<64, 64, 64, 8, 1><<<dim3(64, 8, 2), 64, 0, stream>>>(buf1, WL(4), BL(4), SL(4), buf0);
    // L6: -> [32][128][128]
    bm_kernel<64, 128, 32, 8, 1><<<dim3(32, 16, 2), 64, 0, stream>>>(buf0, WL(5), BL(5), SL(5), buf1);
    // L7: -> [16][256][128]
    bm_kernel<128, 256, 16, 8, 2><<<dim3(16, 32, 2), 128, 0, stream>>>(buf1, WL(6), BL(6), SL(6), buf0);
    // L8: -> [8][512][128]
    bm_kernel<256, 512, 8, 8, 2><<<dim3(8, 64, 2), 128, 0, stream>>>(buf0, WL(7), BL(7), SL(7), buf1);
    // L9: -> [4][512][128]
    bm_kernel<512, 512, 4, 8, 4><<<dim3(4, 64, 2), 256, 0, stream>>>(buf1, WL(8), BL(8), SL(8), buf0);
    // L10: -> [2][512][128]
    bm_kernel<512, 512, 2, 8, 4><<<dim3(2, 64, 2), 256, 0, stream>>>(buf0, WL(9), BL(9), SL(9), buf1);
    // L11: -> [1][1024][128]
    bm_kernel<512, 1024, 1, 8, 4><<<dim3(1, 128, 2), 256, 0, stream>>>(buf1, WL(10), BL(10), SL(10), buf0);

    // FC head (h = buf0, [1024][128])
    fc_logsoftmax_kernel<<<BATCH, 256, 0, stream>>>(buf0, fcW, fcb, (float*)d_out);

#undef WL
#undef BL
#undef SL
}

// Round 5
// 354.424 us; speedup vs baseline: 1.1569x; 1.1569x over previous
//
#include <hip/hip_runtime.h>
#include <math.h>

#define BATCH 128

// ============================================================================
// Layer 1 (fused transpose + conv + select + pool):
// x [128][3][2048] -> X2 [1024][8][128]  (batch-minor)
// ============================================================================
__global__ __launch_bounds__(256) void l1_kernel(
    const float* __restrict__ x, const float* __restrict__ W,
    const float* __restrict__ bias, const int* __restrict__ sel,
    float* __restrict__ Xout)
{
    __shared__ float tile[3][64][65];   // [c][n_local][b_local]
    __shared__ float wl[72];
    __shared__ float bl[24];
    int tid = threadIdx.x;
    int n0 = blockIdx.x * 64;
    int b0 = blockIdx.y * 64;
    if (tid < 72) wl[tid] = W[tid];
    if (tid >= 128 && tid < 152) bl[tid - 128] = bias[tid - 128];

    int ln = tid & 63;
    int bg = tid >> 6;
#pragma unroll
    for (int c = 0; c < 3; ++c)
#pragma unroll
        for (int j = 0; j < 16; ++j) {
            int bloc = bg * 16 + j;
            tile[c][ln][bloc] = x[(size_t)(b0 + bloc) * 6144 + c * 2048 + n0 + ln];
        }
    __syncthreads();

    for (int pp = 0; pp < 8; ++pp) {
        int p  = bg * 8 + pp;
        int ng = n0 + 2 * p;
        int s0 = sel[ng];
        int s1 = sel[ng + 1];
        float xa0 = tile[0][2*p][ln],   xa1 = tile[1][2*p][ln],   xa2 = tile[2][2*p][ln];
        float xb0 = tile[0][2*p+1][ln], xb1 = tile[1][2*p+1][ln], xb2 = tile[2][2*p+1][ln];
        int npair = (n0 >> 1) + p;
#pragma unroll
        for (int f = 0; f < 8; ++f) {
            int r0 = f * 3 + s0, r1 = f * 3 + s1;
            float z0 = fmaf(wl[r0*3+2], xa2, fmaf(wl[r0*3+1], xa1, fmaf(wl[r0*3+0], xa0, bl[r0])));
            float z1 = fmaf(wl[r1*3+2], xb2, fmaf(wl[r1*3+1], xb1, fmaf(wl[r1*3+0], xb0, bl[r1])));
            Xout[((size_t)npair * 8 + f) * 128 + b0 + ln] = fmaxf(fmaxf(z0, z1), 0.f);
        }
    }
}

// ============================================================================
// Unified deep layer kernel (layers 2..11), batch-minor.
//  X [2*NP][CIN][128] -> Xout [NP][CF][128]
//  Block = KS (k-split) x FW (f-split) waves. lane = batch.
//  Wave: TF f-values, 1 n-pair, 64 b, k-chunk of CIN/KS.
//  W read as wave-uniform float4 (original layout), X coalesced scalar.
//  Partials combined through LDS; fused bias+relu+maxpool epilogue.
// ============================================================================
template<int CIN, int CF, int NP, int TF, int KS, int FW>
__global__ __launch_bounds__(64 * KS * FW, 4) void deep_kernel(
    const float* __restrict__ X,
    const float* __restrict__ W,
    const float* __restrict__ bias,
    const int*   __restrict__ sel,
    float* __restrict__ Xout)
{
    constexpr int KC     = CIN / KS;
    constexpr int NTHR   = 64 * KS * FW;
    const int tid  = threadIdx.x;
    const int lane = tid & 63;
    const int wv   = tid >> 6;
    const int kw   = wv % KS;
    const int fw   = wv / KS;
    const int n    = blockIdx.x;
    const int ft   = blockIdx.y;
    const int b0   = blockIdx.z << 6;

    const int s0 = __builtin_amdgcn_readfirstlane(sel[2 * n]);
    const int s1 = __builtin_amdgcn_readfirstlane(sel[2 * n + 1]);

    const int f0 = (ft * FW + fw) * TF;
    const int k0 = kw * KC;

    const float* xp0 = X + ((size_t)(2 * n) * CIN + k0) * 128 + b0 + lane;
    const float* xp1 = xp0 + (size_t)CIN * 128;
    const float* w0p = W + (size_t)(f0 * 3 + s0) * CIN + k0;
    const float* w1p = W + (size_t)(f0 * 3 + s1) * CIN + k0;

    float acc0[TF], acc1[TF];
#pragma unroll
    for (int t = 0; t < TF; ++t) { acc0[t] = 0.f; acc1[t] = 0.f; }

#pragma unroll 2
    for (int kq = 0; kq < KC; kq += 4) {
        float4 wa[TF], wb[TF];
#pragma unroll
        for (int t = 0; t < TF; ++t) {
            wa[t] = *(const float4*)(w0p + (size_t)(3 * t) * CIN + kq);
            wb[t] = *(const float4*)(w1p + (size_t)(3 * t) * CIN + kq);
        }
        float xa0 = xp0[(kq + 0) * 128];
        float xa1 = xp0[(kq + 1) * 128];
        float xa2 = xp0[(kq + 2) * 128];
        float xa3 = xp0[(kq + 3) * 128];
        float xb0 = xp1[(kq + 0) * 128];
        float xb1 = xp1[(kq + 1) * 128];
        float xb2 = xp1[(kq + 2) * 128];
        float xb3 = xp1[(kq + 3) * 128];
#pragma unroll
        for (int t = 0; t < TF; ++t) {
            acc0[t] = fmaf(wa[t].x, xa0, acc0[t]);
            acc0[t] = fmaf(wa[t].y, xa1, acc0[t]);
            acc0[t] = fmaf(wa[t].z, xa2, acc0[t]);
            acc0[t] = fmaf(wa[t].w, xa3, acc0[t]);
            acc1[t] = fmaf(wb[t].x, xb0, acc1[t]);
            acc1[t] = fmaf(wb[t].y, xb1, acc1[t]);
            acc1[t] = fmaf(wb[t].z, xb2, acc1[t]);
            acc1[t] = fmaf(wb[t].w, xb3, acc1[t]);
        }
    }

    // ---- combine K-split partials through LDS ----
    __shared__ float sh[KS][FW][TF][2][64];
#pragma unroll
    for (int t = 0; t < TF; ++t) {
        sh[kw][fw][t][0][lane] = acc0[t];
        sh[kw][fw][t][1][lane] = acc1[t];
    }
    __syncthreads();

    // ---- epilogue: sum over KS, bias+relu+maxpool, coalesced store ----
    constexpr int OUT = FW * TF * 64;
#pragma unroll
    for (int o = tid; o < OUT; o += NTHR) {
        int lo  = o & 63;
        int t   = (o >> 6) % TF;
        int fwo = o / (64 * TF);
        float v0 = 0.f, v1 = 0.f;
#pragma unroll
        for (int k = 0; k < KS; ++k) {
            v0 += sh[k][fwo][t][0][lo];
            v1 += sh[k][fwo][t][1][lo];
        }
        int f = (ft * FW + fwo) * TF + t;
        v0 += bias[f * 3 + s0];
        v1 += bias[f * 3 + s1];
        Xout[((size_t)n * CF + f) * 128 + b0 + lo] = fmaxf(fmaxf(v0, v1), 0.f);
    }
}

// ============================================================================
// FC head: h batch-minor [1024][128]; out [128][16] log-softmax
// ============================================================================
__global__ __launch_bounds__(256) void fc_logsoftmax_kernel(
    const float* __restrict__ h, const float* __restrict__ fcW,
    const float* __restrict__ fcb, float* __restrict__ out)
{
    int b   = blockIdx.x;
    int tid = threadIdx.x;
    int k     = tid & 15;
    int chunk = tid >> 4;

    const float* __restrict__ wk = fcW + (size_t)k * 1024;

    float partial = 0.0f;
    int j0 = chunk * 64;
#pragma unroll 8
    for (int j = 0; j < 64; ++j)
        partial = fmaf(h[(size_t)(j0 + j) * 128 + b], wk[j0 + j], partial);

    __shared__ float red[16][17];
    red[chunk][k] = partial;
    __syncthreads();

    __shared__ float logits[16];
    if (tid < 16) {
        float s = fcb[tid];
#pragma unroll
        for (int c = 0; c < 16; ++c) s += red[c][tid];
        logits[tid] = s;
    }
    __syncthreads();

    if (tid < 16) {
        float mx = -INFINITY;
#pragma unroll
        for (int kk = 0; kk < 16; ++kk) mx = fmaxf(mx, logits[kk]);
        float se = 0.0f;
#pragma unroll
        for (int kk = 0; kk < 16; ++kk) se += expf(logits[kk] - mx);
        out[b * 16 + tid] = logits[tid] - mx - logf(se);
    }
}

// ============================================================================
extern "C" void kernel_launch(void* const* d_in, const int* in_sizes, int n_in,
                              void* d_out, int out_size, void* d_ws, size_t ws_size,
                              hipStream_t stream)
{
    const float* x   = (const float*)d_in[0];
    const float* fcW = (const float*)d_in[34];
    const float* fcb = (const float*)d_in[35];

    float* buf0 = (float*)d_ws;
    float* buf1 = (float*)d_ws + (2u * 1024u * 1024u);   // 8 MB slots

#define WL(i) (const float*)d_in[1 + 3 * (i)]
#define BL(i) (const float*)d_in[2 + 3 * (i)]
#define SL(i) (const int*)  d_in[3 + 3 * (i)]

    // L1: x -> buf0  X2 [1024][8][128]
    l1_kernel<<<dim3(32, 2), 256, 0, stream>>>(x, WL(0), BL(0), SL(0), buf0);

    // L2:  [1024][8][128] -> [512][32][128]     8192 waves
    deep_kernel<8, 32, 512, 8, 2, 2><<<dim3(512, 2, 2), 256, 0, stream>>>(buf0, WL(1), BL(1), SL(1), buf1);
    // L3:  -> [256][64][128]                    8192 waves
    deep_kernel<32, 64, 256, 8, 2, 2><<<dim3(256, 4, 2), 256, 0, stream>>>(buf1, WL(2), BL(2), SL(2), buf0);
    // L4:  -> [128][64][128]                    8192 waves
    deep_kernel<64, 64, 128, 8, 4, 2><<<dim3(128, 4, 2), 512, 0, stream>>>(buf0, WL(3), BL(3), SL(3), buf1);
    // L5:  -> [64][64][128]                     4096 waves
    deep_kernel<64, 64, 64, 8, 4, 2><<<dim3(64, 4, 2), 512, 0, stream>>>(buf1, WL(4), BL(4), SL(4), buf0);
    // L6:  -> [32][128][128]                    4096 waves
    deep_kernel<64, 128, 32, 8, 4, 2><<<dim3(32, 8, 2), 512, 0, stream>>>(buf0, WL(5), BL(5), SL(5), buf1);
    // L7:  -> [16][256][128]                    4096 waves
    deep_kernel<128, 256, 16, 8, 4, 2><<<dim3(16, 16, 2), 512, 0, stream>>>(buf1, WL(6), BL(6), SL(6), buf0);
    // L8:  -> [8][512][128]                     8192 waves
    deep_kernel<256, 512, 8, 8, 8, 2><<<dim3(8, 32, 2), 1024, 0, stream>>>(buf0, WL(7), BL(7), SL(7), buf1);
    // L9:  -> [4][512][128]                     4096 waves
    deep_kernel<512, 512, 4, 8, 8, 2><<<dim3(4, 32, 2), 1024, 0, stream>>>(buf1, WL(8), BL(8), SL(8), buf0);
    // L10: -> [2][512][128]                     4096 waves
    deep_kernel<512, 512, 2, 8, 16, 1><<<dim3(2, 64, 2), 1024, 0, stream>>>(buf0, WL(9), BL(9), SL(9), buf1);
    // L11: -> [1][1024][128]                    4096 waves
    deep_kernel<512, 1024, 1, 8, 16, 1><<<dim3(1, 128, 2), 1024, 0, stream>>>(buf1, WL(10), BL(10), SL(10), buf0);

    // FC head (h = buf0, [1024][128])
    fc_logsoftmax_kernel<<<BATCH, 256, 0, stream>>>(buf0, fcW, fcb, (float*)d_out);

#undef WL
#undef BL
#undef SL
}

// Round 6
// 344.860 us; speedup vs baseline: 1.1890x; 1.0277x over previous
//
#include <hip/hip_runtime.h>
#include <math.h>

#define BATCH 128

// ============================================================================
// Layer 1 (fused transpose + conv + select + pool):
// x [128][3][2048] -> X2 [1024][8][128]  (batch-minor)
// ============================================================================
__global__ __launch_bounds__(256) void l1_kernel(
    const float* __restrict__ x, const float* __restrict__ W,
    const float* __restrict__ bias, const int* __restrict__ sel,
    float* __restrict__ Xout)
{
    __shared__ float tile[3][64][65];   // [c][n_local][b_local]
    __shared__ float wl[72];
    __shared__ float bl[24];
    int tid = threadIdx.x;
    int n0 = blockIdx.x * 64;
    int b0 = blockIdx.y * 64;
    if (tid < 72) wl[tid] = W[tid];
    if (tid >= 128 && tid < 152) bl[tid - 128] = bias[tid - 128];

    int ln = tid & 63;
    int bg = tid >> 6;
#pragma unroll
    for (int c = 0; c < 3; ++c)
#pragma unroll
        for (int j = 0; j < 16; ++j) {
            int bloc = bg * 16 + j;
            tile[c][ln][bloc] = x[(size_t)(b0 + bloc) * 6144 + c * 2048 + n0 + ln];
        }
    __syncthreads();

    for (int pp = 0; pp < 8; ++pp) {
        int p  = bg * 8 + pp;
        int ng = n0 + 2 * p;
        int s0 = sel[ng];
        int s1 = sel[ng + 1];
        float xa0 = tile[0][2*p][ln],   xa1 = tile[1][2*p][ln],   xa2 = tile[2][2*p][ln];
        float xb0 = tile[0][2*p+1][ln], xb1 = tile[1][2*p+1][ln], xb2 = tile[2][2*p+1][ln];
        int npair = (n0 >> 1) + p;
#pragma unroll
        for (int f = 0; f < 8; ++f) {
            int r0 = f * 3 + s0, r1 = f * 3 + s1;
            float z0 = fmaf(wl[r0*3+2], xa2, fmaf(wl[r0*3+1], xa1, fmaf(wl[r0*3+0], xa0, bl[r0])));
            float z1 = fmaf(wl[r1*3+2], xb2, fmaf(wl[r1*3+1], xb1, fmaf(wl[r1*3+0], xb0, bl[r1])));
            Xout[((size_t)npair * 8 + f) * 128 + b0 + ln] = fmaxf(fmaxf(z0, z1), 0.f);
        }
    }
}

// ============================================================================
// Unified deep layer kernel (layers 2..11), batch-minor, TB=2 (float2 batch).
//  X [2*NP][CIN][128] -> Xout [NP][CF][128]
//  Block = KS (k-split) x FW (f-split) waves. Lane owns batches 2l, 2l+1.
//  Wave: TF f-values, 1 n-pair, 128 b (as float2), k-chunk of CIN/KS.
//  W read as wave-uniform float4 (original layout), X coalesced float2.
//  K-split partials combined through LDS; fused bias+relu+maxpool epilogue.
// ============================================================================
template<int CIN, int CF, int NP, int TF, int KS, int FW>
__global__ __launch_bounds__(64 * KS * FW) void deep_kernel(
    const float* __restrict__ X,
    const float* __restrict__ W,
    const float* __restrict__ bias,
    const int*   __restrict__ sel,
    float* __restrict__ Xout)
{
    constexpr int KC   = CIN / KS;
    constexpr int NTHR = 64 * KS * FW;
    const int tid  = threadIdx.x;
    const int lane = tid & 63;
    const int wv   = tid >> 6;
    const int kw   = (KS > 1) ? (wv % KS) : 0;
    const int fw   = (KS > 1) ? (wv / KS) : wv;
    const int n    = blockIdx.x;
    const int ft   = blockIdx.y;

    const int s0 = __builtin_amdgcn_readfirstlane(sel[2 * n]);
    const int s1 = __builtin_amdgcn_readfirstlane(sel[2 * n + 1]);

    const int f0 = (ft * FW + fw) * TF;
    const int k0 = kw * KC;

    const float* xp0 = X + ((size_t)(2 * n) * CIN + k0) * 128 + 2 * lane;
    const float* xp1 = xp0 + (size_t)CIN * 128;
    const float* w0p = W + (size_t)(f0 * 3 + s0) * CIN + k0;
    const float* w1p = W + (size_t)(f0 * 3 + s1) * CIN + k0;

    float2 acc0[TF], acc1[TF];
#pragma unroll
    for (int t = 0; t < TF; ++t) {
        acc0[t] = make_float2(0.f, 0.f);
        acc1[t] = make_float2(0.f, 0.f);
    }

#pragma unroll 4
    for (int kq = 0; kq < KC; kq += 4) {
        float4 wa[TF], wb[TF];
#pragma unroll
        for (int t = 0; t < TF; ++t) {
            wa[t] = *(const float4*)(w0p + (size_t)(3 * t) * CIN + kq);
            wb[t] = *(const float4*)(w1p + (size_t)(3 * t) * CIN + kq);
        }
        float2 xa[4], xb[4];
#pragma unroll
        for (int k = 0; k < 4; ++k) {
            xa[k] = *(const float2*)(xp0 + (size_t)(kq + k) * 128);
            xb[k] = *(const float2*)(xp1 + (size_t)(kq + k) * 128);
        }
#pragma unroll
        for (int t = 0; t < TF; ++t) {
            acc0[t].x = fmaf(wa[t].x, xa[0].x, acc0[t].x);
            acc0[t].y = fmaf(wa[t].x, xa[0].y, acc0[t].y);
            acc0[t].x = fmaf(wa[t].y, xa[1].x, acc0[t].x);
            acc0[t].y = fmaf(wa[t].y, xa[1].y, acc0[t].y);
            acc0[t].x = fmaf(wa[t].z, xa[2].x, acc0[t].x);
            acc0[t].y = fmaf(wa[t].z, xa[2].y, acc0[t].y);
            acc0[t].x = fmaf(wa[t].w, xa[3].x, acc0[t].x);
            acc0[t].y = fmaf(wa[t].w, xa[3].y, acc0[t].y);
            acc1[t].x = fmaf(wb[t].x, xb[0].x, acc1[t].x);
            acc1[t].y = fmaf(wb[t].x, xb[0].y, acc1[t].y);
            acc1[t].x = fmaf(wb[t].y, xb[1].x, acc1[t].x);
            acc1[t].y = fmaf(wb[t].y, xb[1].y, acc1[t].y);
            acc1[t].x = fmaf(wb[t].z, xb[2].x, acc1[t].x);
            acc1[t].y = fmaf(wb[t].z, xb[2].y, acc1[t].y);
            acc1[t].x = fmaf(wb[t].w, xb[3].x, acc1[t].x);
            acc1[t].y = fmaf(wb[t].w, xb[3].y, acc1[t].y);
        }
    }

    if constexpr (KS == 1) {
        // direct store, no LDS
#pragma unroll
        for (int t = 0; t < TF; ++t) {
            int f = f0 + t;
            float bi0 = bias[f * 3 + s0];
            float bi1 = bias[f * 3 + s1];
            float2 v;
            v.x = fmaxf(fmaxf(acc0[t].x + bi0, acc1[t].x + bi1), 0.f);
            v.y = fmaxf(fmaxf(acc0[t].y + bi0, acc1[t].y + bi1), 0.f);
            *(float2*)(Xout + ((size_t)n * CF + f) * 128 + 2 * lane) = v;
        }
    } else {
        __shared__ float2 sh[KS][FW][TF][2][64];
#pragma unroll
        for (int t = 0; t < TF; ++t) {
            sh[kw][fw][t][0][lane] = acc0[t];
            sh[kw][fw][t][1][lane] = acc1[t];
        }
        __syncthreads();

        constexpr int OUT = FW * TF * 64;   // float2 units
#pragma unroll
        for (int o = tid; o < OUT; o += NTHR) {
            int lo  = o & 63;
            int t   = (o >> 6) % TF;
            int fwo = o / (64 * TF);
            float2 v0 = make_float2(0.f, 0.f), v1 = make_float2(0.f, 0.f);
#pragma unroll
            for (int k = 0; k < KS; ++k) {
                float2 a = sh[k][fwo][t][0][lo];
                float2 b = sh[k][fwo][t][1][lo];
                v0.x += a.x; v0.y += a.y;
                v1.x += b.x; v1.y += b.y;
            }
            int f = (ft * FW + fwo) * TF + t;
            float bi0 = bias[f * 3 + s0];
            float bi1 = bias[f * 3 + s1];
            float2 v;
            v.x = fmaxf(fmaxf(v0.x + bi0, v1.x + bi1), 0.f);
            v.y = fmaxf(fmaxf(v0.y + bi0, v1.y + bi1), 0.f);
            *(float2*)(Xout + ((size_t)n * CF + f) * 128 + 2 * lo) = v;
        }
    }
}

// ============================================================================
// FC head: h batch-minor [1024][128]; out [128][16] log-softmax
// ============================================================================
__global__ __launch_bounds__(256) void fc_logsoftmax_kernel(
    const float* __restrict__ h, const float* __restrict__ fcW,
    const float* __restrict__ fcb, float* __restrict__ out)
{
    int b   = blockIdx.x;
    int tid = threadIdx.x;
    int k     = tid & 15;
    int chunk = tid >> 4;

    const float* __restrict__ wk = fcW + (size_t)k * 1024;

    float partial = 0.0f;
    int j0 = chunk * 64;
#pragma unroll 8
    for (int j = 0; j < 64; ++j)
        partial = fmaf(h[(size_t)(j0 + j) * 128 + b], wk[j0 + j], partial);

    __shared__ float red[16][17];
    red[chunk][k] = partial;
    __syncthreads();

    __shared__ float logits[16];
    if (tid < 16) {
        float s = fcb[tid];
#pragma unroll
        for (int c = 0; c < 16; ++c) s += red[c][tid];
        logits[tid] = s;
    }
    __syncthreads();

    if (tid < 16) {
        float mx = -INFINITY;
#pragma unroll
        for (int kk = 0; kk < 16; ++kk) mx = fmaxf(mx, logits[kk]);
        float se = 0.0f;
#pragma unroll
        for (int kk = 0; kk < 16; ++kk) se += expf(logits[kk] - mx);
        out[b * 16 + tid] = logits[tid] - mx - logf(se);
    }
}

// ============================================================================
extern "C" void kernel_launch(void* const* d_in, const int* in_sizes, int n_in,
                              void* d_out, int out_size, void* d_ws, size_t ws_size,
                              hipStream_t stream)
{
    const float* x   = (const float*)d_in[0];
    const float* fcW = (const float*)d_in[34];
    const float* fcb = (const float*)d_in[35];

    float* buf0 = (float*)d_ws;
    float* buf1 = (float*)d_ws + (2u * 1024u * 1024u);   // 8 MB slots

#define WL(i) (const float*)d_in[1 + 3 * (i)]
#define BL(i) (const float*)d_in[2 + 3 * (i)]
#define SL(i) (const int*)  d_in[3 + 3 * (i)]

    // L1: x -> buf0  X2 [1024][8][128]
    l1_kernel<<<dim3(32, 2), 256, 0, stream>>>(x, WL(0), BL(0), SL(0), buf0);

    // All deep layers: 4096 waves each.
    // L2:  [1024][8][128] -> [512][32][128]
    deep_kernel<8, 32, 512, 4, 1, 1><<<dim3(512, 8), 64, 0, stream>>>(buf0, WL(1), BL(1), SL(1), buf1);
    // L3:  -> [256][64][128]
    deep_kernel<32, 64, 256, 4, 1, 1><<<dim3(256, 16), 64, 0, stream>>>(buf1, WL(2), BL(2), SL(2), buf0);
    // L4:  -> [128][64][128]
    deep_kernel<64, 64, 128, 4, 2, 1><<<dim3(128, 16), 128, 0, stream>>>(buf0, WL(3), BL(3), SL(3), buf1);
    // L5:  -> [64][64][128]
    deep_kernel<64, 64, 64, 4, 4, 1><<<dim3(64, 16), 256, 0, stream>>>(buf1, WL(4), BL(4), SL(4), buf0);
    // L6:  -> [32][128][128]
    deep_kernel<64, 128, 32, 4, 4, 1><<<dim3(32, 32), 256, 0, stream>>>(buf0, WL(5), BL(5), SL(5), buf1);
    // L7:  -> [16][256][128]
    deep_kernel<128, 256, 16, 4, 4, 1><<<dim3(16, 64), 256, 0, stream>>>(buf1, WL(6), BL(6), SL(6), buf0);
    // L8:  -> [8][512][128]
    deep_kernel<256, 512, 8, 4, 4, 1><<<dim3(8, 128), 256, 0, stream>>>(buf0, WL(7), BL(7), SL(7), buf1);
    // L9:  -> [4][512][128]  (LDS 32 KB)
    deep_kernel<512, 512, 4, 4, 8, 1><<<dim3(4, 128), 512, 0, stream>>>(buf1, WL(8), BL(8), SL(8), buf0);
    // L10: -> [2][512][128]
    deep_kernel<512, 512, 2, 2, 8, 1><<<dim3(2, 256), 512, 0, stream>>>(buf0, WL(9), BL(9), SL(9), buf1);
    // L11: -> [1][1024][128]
    deep_kernel<512, 1024, 1, 2, 8, 1><<<dim3(1, 512), 512, 0, stream>>>(buf1, WL(10), BL(10), SL(10), buf0);

    // FC head (h = buf0, [1024][128])
    fc_logsoftmax_kernel<<<BATCH, 256, 0, stream>>>(buf0, fcW, fcb, (float*)d_out);

#undef WL
#undef BL
#undef SL
}

// Round 7
// 321.774 us; speedup vs baseline: 1.2743x; 1.0717x over previous
//
#include <hip/hip_runtime.h>
#include <math.h>

#define BATCH 128

// ============================================================================
// Layer 1 (fused transpose + conv + select + pool):
// x [128][3][2048] -> X2 [1024][8][128]  (batch-minor)
// ============================================================================
__global__ __launch_bounds__(256) void l1_kernel(
    const float* __restrict__ x, const float* __restrict__ W,
    const float* __restrict__ bias, const int* __restrict__ sel,
    float* __restrict__ Xout)
{
    __shared__ float tile[3][64][65];   // [c][n_local][b_local]
    __shared__ float wl[72];
    __shared__ float bl[24];
    int tid = threadIdx.x;
    int n0 = blockIdx.x * 64;
    int b0 = blockIdx.y * 64;
    if (tid < 72) wl[tid] = W[tid];
    if (tid >= 128 && tid < 152) bl[tid - 128] = bias[tid - 128];

    int ln = tid & 63;
    int bg = tid >> 6;
#pragma unroll
    for (int c = 0; c < 3; ++c)
#pragma unroll
        for (int j = 0; j < 16; ++j) {
            int bloc = bg * 16 + j;
            tile[c][ln][bloc] = x[(size_t)(b0 + bloc) * 6144 + c * 2048 + n0 + ln];
        }
    __syncthreads();

    for (int pp = 0; pp < 8; ++pp) {
        int p  = bg * 8 + pp;
        int ng = n0 + 2 * p;
        int s0 = sel[ng];
        int s1 = sel[ng + 1];
        float xa0 = tile[0][2*p][ln],   xa1 = tile[1][2*p][ln],   xa2 = tile[2][2*p][ln];
        float xb0 = tile[0][2*p+1][ln], xb1 = tile[1][2*p+1][ln], xb2 = tile[2][2*p+1][ln];
        int npair = (n0 >> 1) + p;
#pragma unroll
        for (int f = 0; f < 8; ++f) {
            int r0 = f * 3 + s0, r1 = f * 3 + s1;
            float z0 = fmaf(wl[r0*3+2], xa2, fmaf(wl[r0*3+1], xa1, fmaf(wl[r0*3+0], xa0, bl[r0])));
            float z1 = fmaf(wl[r1*3+2], xb2, fmaf(wl[r1*3+1], xb1, fmaf(wl[r1*3+0], xb0, bl[r1])));
            Xout[((size_t)npair * 8 + f) * 128 + b0 + ln] = fmaxf(fmaxf(z0, z1), 0.f);
        }
    }
}

// ============================================================================
// Layer 2 (CIN=8, CF=32): small-K special case, W preloaded to registers.
// X [1024][8][128] -> Xout [512][32][128]. 1 wave/block, lane owns b float2.
// ============================================================================
__global__ __launch_bounds__(64) void l2_kernel(
    const float* __restrict__ X, const float* __restrict__ W,
    const float* __restrict__ bias, const int* __restrict__ sel,
    float* __restrict__ Xout)
{
    const int lane = threadIdx.x;
    const int n  = blockIdx.x;
    const int f0 = blockIdx.y * 4;
    const int s0 = sel[2 * n], s1 = sel[2 * n + 1];

    // preload W rows: 4 f x 2 sel x 8 k
    float4 wa[4][2], wb[4][2];
#pragma unroll
    for (int t = 0; t < 4; ++t) {
        const float* r0 = W + (size_t)((f0 + t) * 3 + s0) * 8;
        const float* r1 = W + (size_t)((f0 + t) * 3 + s1) * 8;
        wa[t][0] = *(const float4*)r0;  wa[t][1] = *(const float4*)(r0 + 4);
        wb[t][0] = *(const float4*)r1;  wb[t][1] = *(const float4*)(r1 + 4);
    }

    const float* xp0 = X + (size_t)(2 * n) * 8 * 128 + 2 * lane;
    const float* xp1 = xp0 + 8 * 128;

    float2 acc0[4], acc1[4];
#pragma unroll
    for (int t = 0; t < 4; ++t) { acc0[t] = make_float2(0.f,0.f); acc1[t] = make_float2(0.f,0.f); }

#pragma unroll
    for (int k = 0; k < 8; ++k) {
        float2 xa = *(const float2*)(xp0 + k * 128);
        float2 xb = *(const float2*)(xp1 + k * 128);
#pragma unroll
        for (int t = 0; t < 4; ++t) {
            float wva = (k < 4) ? ((const float*)&wa[t][0])[k] : ((const float*)&wa[t][1])[k-4];
            float wvb = (k < 4) ? ((const float*)&wb[t][0])[k] : ((const float*)&wb[t][1])[k-4];
            acc0[t].x = fmaf(wva, xa.x, acc0[t].x);
            acc0[t].y = fmaf(wva, xa.y, acc0[t].y);
            acc1[t].x = fmaf(wvb, xb.x, acc1[t].x);
            acc1[t].y = fmaf(wvb, xb.y, acc1[t].y);
        }
    }

#pragma unroll
    for (int t = 0; t < 4; ++t) {
        int f = f0 + t;
        float bi0 = bias[f * 3 + s0];
        float bi1 = bias[f * 3 + s1];
        float2 v;
        v.x = fmaxf(fmaxf(acc0[t].x + bi0, acc1[t].x + bi1), 0.f);
        v.y = fmaxf(fmaxf(acc0[t].y + bi0, acc1[t].y + bi1), 0.f);
        *(float2*)(Xout + ((size_t)n * 32 + f) * 128 + 2 * lane) = v;
    }
}

// ============================================================================
// LDS-tiled layer kernel (layers 3..11), batch-minor.
//  X [2*NP][CIN][128] -> Xout [NP][CF][128]
//  Block: FW (f-split) x KW (k-split) waves. Lane owns batch float2, both pos.
//  W staged ONCE to LDS (transposed to [pos][k][f], coalesced global reads);
//  X staged per BK=32 chunk to LDS (fully coalesced), shared by all waves.
//  Compute: per k, 2 X float2 reads + 4 W b128 broadcasts + 32 FMA.
//  K-split partials tree-reduced through the X LDS buffer.
// ============================================================================
template<int CIN, int CF, int NP, int FW, int KW>
__global__ __launch_bounds__(64 * FW * KW) void tile_kernel(
    const float* __restrict__ X,
    const float* __restrict__ W,
    const float* __restrict__ bias,
    const int*   __restrict__ sel,
    float* __restrict__ Xout)
{
    constexpr int TF     = 8;
    constexpr int BK     = 32;
    constexpr int NW     = FW * KW;
    constexpr int NTHR   = 64 * NW;
    constexpr int FBLK   = FW * TF;
    constexpr int KSUB   = BK / KW;
    constexpr int NCHUNK = CIN / BK;
    constexpr int PAD    = (FBLK == 8) ? 0 : 4;

    __shared__ float Wl[2][CIN][FBLK + PAD];
    __shared__ float Xl[2 * BK * 128];     // 32 KB; reused as reduce scratch

    const int tid  = threadIdx.x;
    const int lane = tid & 63;
    const int wv   = tid >> 6;
    const int kw   = wv % KW;
    const int fw   = wv / KW;
    const int n    = blockIdx.x;
    const int f0   = blockIdx.y * FBLK;
    const int fl   = fw * TF;

    const int s0 = sel[2 * n];
    const int s1 = sel[2 * n + 1];

    // ---- stage W once: Wl[p][k][fj] = W[(f0+fj)*3+s_p][k], coalesced along k
    constexpr int KV = CIN / 4;
    for (int v = tid; v < 2 * FBLK * KV; v += NTHR) {
        int kq = v % KV;
        int r  = v / KV;
        int fj = r % FBLK;
        int p  = r / FBLK;
        int s  = p ? s1 : s0;
        float4 w4 = *(const float4*)(W + (size_t)((f0 + fj) * 3 + s) * CIN + 4 * kq);
        Wl[p][4*kq+0][fj] = w4.x;
        Wl[p][4*kq+1][fj] = w4.y;
        Wl[p][4*kq+2][fj] = w4.z;
        Wl[p][4*kq+3][fj] = w4.w;
    }

    float2 acc0[TF], acc1[TF];
#pragma unroll
    for (int t = 0; t < TF; ++t) { acc0[t] = make_float2(0.f,0.f); acc1[t] = make_float2(0.f,0.f); }

    for (int c = 0; c < NCHUNK; ++c) {
        __syncthreads();   // protect Xl from previous chunk's readers (and c=0 no-op)
        // ---- stage X chunk [2][BK][128], fully coalesced float4
        const float* src = X + ((size_t)(2 * n) * CIN + c * BK) * 128;
        constexpr int XV = 2 * BK * 32;    // float4 count
        for (int v = tid; v < XV; v += NTHR) {
            int col4 = v & 31;
            int kk   = (v >> 5) % BK;
            int p    = v / (32 * BK);
            float4 x4 = *(const float4*)(src + ((size_t)p * CIN + kk) * 128 + 4 * col4);
            *(float4*)&Xl[(size_t)(p * BK + kk) * 128 + 4 * col4] = x4;
        }
        __syncthreads();

        // ---- compute: wave kw covers kk in [kw*KSUB, (kw+1)*KSUB)
#pragma unroll 4
        for (int kk = 0; kk < KSUB; ++kk) {
            int klocal = kw * KSUB + kk;
            int kg = c * BK + klocal;
            float2 xa = *(const float2*)&Xl[(size_t)klocal * 128 + 2 * lane];
            float2 xb = *(const float2*)&Xl[(size_t)(BK + klocal) * 128 + 2 * lane];
            float4 a0 = *(const float4*)&Wl[0][kg][fl];
            float4 a1 = *(const float4*)&Wl[0][kg][fl + 4];
            float4 b0 = *(const float4*)&Wl[1][kg][fl];
            float4 b1 = *(const float4*)&Wl[1][kg][fl + 4];
            float wa[8] = {a0.x,a0.y,a0.z,a0.w,a1.x,a1.y,a1.z,a1.w};
            float wb[8] = {b0.x,b0.y,b0.z,b0.w,b1.x,b1.y,b1.z,b1.w};
#pragma unroll
            for (int t = 0; t < TF; ++t) {
                acc0[t].x = fmaf(wa[t], xa.x, acc0[t].x);
                acc0[t].y = fmaf(wa[t], xa.y, acc0[t].y);
                acc1[t].x = fmaf(wb[t], xb.x, acc1[t].x);
                acc1[t].y = fmaf(wb[t], xb.y, acc1[t].y);
            }
        }
    }

    // ---- tree-reduce k-split partials through Xl (slots of 1024 float2)
    if constexpr (KW > 1) {
        float2* Xl2 = (float2*)Xl;
        for (int h = KW / 2; h >= 1; h >>= 1) {
            __syncthreads();
            if (kw >= h && kw < 2 * h) {
                int slot = fw * h + (kw - h);
                float2* dst = Xl2 + (size_t)slot * 1024 + lane;
#pragma unroll
                for (int t = 0; t < TF; ++t) {
                    dst[t * 64]        = acc0[t];
                    dst[(TF + t) * 64] = acc1[t];
                }
            }
            __syncthreads();
            if (kw < h) {
                const float2* s2 = Xl2 + (size_t)(fw * h + kw) * 1024 + lane;
#pragma unroll
                for (int t = 0; t < TF; ++t) {
                    float2 a = s2[t * 64];
                    float2 b = s2[(TF + t) * 64];
                    acc0[t].x += a.x; acc0[t].y += a.y;
                    acc1[t].x += b.x; acc1[t].y += b.y;
                }
            }
        }
    }

    // ---- epilogue: bias + relu + maxpool, coalesced float2 store
    if (kw == 0) {
#pragma unroll
        for (int t = 0; t < TF; ++t) {
            int f = f0 + fl + t;
            float bi0 = bias[f * 3 + s0];
            float bi1 = bias[f * 3 + s1];
            float2 v;
            v.x = fmaxf(fmaxf(acc0[t].x + bi0, acc1[t].x + bi1), 0.f);
            v.y = fmaxf(fmaxf(acc0[t].y + bi0, acc1[t].y + bi1), 0.f);
            *(float2*)(Xout + ((size_t)n * CF + f) * 128 + 2 * lane) = v;
        }
    }
}

// ============================================================================
// FC head: h batch-minor [1024][128]; out [128][16] log-softmax
// ============================================================================
__global__ __launch_bounds__(256) void fc_logsoftmax_kernel(
    const float* __restrict__ h, const float* __restrict__ fcW,
    const float* __restrict__ fcb, float* __restrict__ out)
{
    int b   = blockIdx.x;
    int tid = threadIdx.x;
    int k     = tid & 15;
    int chunk = tid >> 4;

    const float* __restrict__ wk = fcW + (size_t)k * 1024;

    float partial = 0.0f;
    int j0 = chunk * 64;
#pragma unroll 8
    for (int j = 0; j < 64; ++j)
        partial = fmaf(h[(size_t)(j0 + j) * 128 + b], wk[j0 + j], partial);

    __shared__ float red[16][17];
    red[chunk][k] = partial;
    __syncthreads();

    __shared__ float logits[16];
    if (tid < 16) {
        float s = fcb[tid];
#pragma unroll
        for (int c = 0; c < 16; ++c) s += red[c][tid];
        logits[tid] = s;
    }
    __syncthreads();

    if (tid < 16) {
        float mx = -INFINITY;
#pragma unroll
        for (int kk = 0; kk < 16; ++kk) mx = fmaxf(mx, logits[kk]);
        float se = 0.0f;
#pragma unroll
        for (int kk = 0; kk < 16; ++kk) se += expf(logits[kk] - mx);
        out[b * 16 + tid] = logits[tid] - mx - logf(se);
    }
}

// ============================================================================
extern "C" void kernel_launch(void* const* d_in, const int* in_sizes, int n_in,
                              void* d_out, int out_size, void* d_ws, size_t ws_size,
                              hipStream_t stream)
{
    const float* x   = (const float*)d_in[0];
    const float* fcW = (const float*)d_in[34];
    const float* fcb = (const float*)d_in[35];

    float* buf0 = (float*)d_ws;
    float* buf1 = (float*)d_ws + (2u * 1024u * 1024u);   // 8 MB slots

#define WL(i) (const float*)d_in[1 + 3 * (i)]
#define BL(i) (const float*)d_in[2 + 3 * (i)]
#define SL(i) (const int*)  d_in[3 + 3 * (i)]

    // L1: x -> buf0  [1024][8][128]
    l1_kernel<<<dim3(32, 2), 256, 0, stream>>>(x, WL(0), BL(0), SL(0), buf0);
    // L2: -> [512][32][128]
    l2_kernel<<<dim3(512, 8), 64, 0, stream>>>(buf0, WL(1), BL(1), SL(1), buf1);

    // L3: -> [256][64][128]   FW=4 KW=1, 512 blocks
    tile_kernel<32, 64, 256, 4, 1><<<dim3(256, 2), 256, 0, stream>>>(buf1, WL(2), BL(2), SL(2), buf0);
    // L4: -> [128][64][128]   FW=2 KW=2, 512 blocks
    tile_kernel<64, 64, 128, 2, 2><<<dim3(128, 4), 256, 0, stream>>>(buf0, WL(3), BL(3), SL(3), buf1);
    // L5: -> [64][64][128]    FW=1 KW=4, 512 blocks
    tile_kernel<64, 64, 64, 1, 4><<<dim3(64, 8), 256, 0, stream>>>(buf1, WL(4), BL(4), SL(4), buf0);
    // L6: -> [32][128][128]   FW=1 KW=4, 512 blocks
    tile_kernel<64, 128, 32, 1, 4><<<dim3(32, 16), 256, 0, stream>>>(buf0, WL(5), BL(5), SL(5), buf1);
    // L7: -> [16][256][128]   FW=1 KW=4, 512 blocks
    tile_kernel<128, 256, 16, 1, 4><<<dim3(16, 32), 256, 0, stream>>>(buf1, WL(6), BL(6), SL(6), buf0);
    // L8: -> [8][512][128]    FW=1 KW=8, 512 blocks
    tile_kernel<256, 512, 8, 1, 8><<<dim3(8, 64), 512, 0, stream>>>(buf0, WL(7), BL(7), SL(7), buf1);
    // L9: -> [4][512][128]    FW=1 KW=8, 256 blocks
    tile_kernel<512, 512, 4, 1, 8><<<dim3(4, 64), 512, 0, stream>>>(buf1, WL(8), BL(8), SL(8), buf0);
    // L10: -> [2][512][128]   FW=1 KW=8, 128 blocks
    tile_kernel<512, 512, 2, 1, 8><<<dim3(2, 64), 512, 0, stream>>>(buf0, WL(9), BL(9), SL(9), buf1);
    // L11: -> [1][1024][128]  FW=1 KW=8, 128 blocks
    tile_kernel<512, 1024, 1, 1, 8><<<dim3(1, 128), 512, 0, stream>>>(buf1, WL(10), BL(10), SL(10), buf0);

    // FC head (h = buf0, [1024][128])
    fc_logsoftmax_kernel<<<BATCH, 256, 0, stream>>>(buf0, fcW, fcb, (float*)d_out);

#undef WL
#undef BL
#undef SL
}